// Round 17
// baseline (27.223 us; speedup 1.0000x reference)
//
#include <hip/hip_runtime.h>

// 5x5 median, replicate borders, C=3, H=W=2048, fp32.
// R17 = R15 (4-row vertical sharing, packed-bf16 network, XCD swizzle)
//     + NON-TEMPORAL output stores via ext_vector_type (fixes R16 compile:
//       the builtin rejects HIP_vector_type uint4, accepts native vectors).
//       Output is write-once -> bypass L2 retention, keep input halos hot.

typedef unsigned int u32;
typedef u32 u32x4 __attribute__((ext_vector_type(4)));

__device__ __forceinline__ u32 pmn(u32 a, u32 b) {
    u32 r;
    asm("v_pk_min_u16 %0, %1, %2" : "=v"(r) : "v"(a), "v"(b));
    return r;
}
__device__ __forceinline__ u32 pmx(u32 a, u32 b) {
    u32 r;
    asm("v_pk_max_u16 %0, %1, %2" : "=v"(r) : "v"(a), "v"(b));
    return r;
}

// Batcher odd-even merge of two sorted 5-arrays -> sorted 10 (packed). 13 CEs.
__device__ __forceinline__ void merge55p(const u32 (&A)[5], const u32 (&B)[5], u32 (&C)[10]) {
    u32 re0 = pmn(A[0], B[0]), re1 = pmx(A[0], B[0]);
    u32 ro0 = pmn(A[4], B[4]), ro1 = pmx(A[4], B[4]);
    u32 R1 = pmn(re1, ro0), R2 = pmx(re1, ro0);
    u32 s0 = pmn(A[2], B[2]), s1 = pmx(A[2], B[2]);
    u32 P1 = pmn(R1, s0), P2 = pmx(R1, s0);
    u32 P3 = pmn(R2, s1), P4 = pmx(R2, s1);
    u32 qe0 = pmn(A[1], B[1]), qe1 = pmx(A[1], B[1]);
    u32 qo0 = pmn(A[3], B[3]), qo1 = pmx(A[3], B[3]);
    u32 Q1 = pmn(qe1, qo0), Q2 = pmx(qe1, qo0);
    C[0] = re0;
    C[1] = pmn(P1, qe0); C[2] = pmx(P1, qe0);
    C[3] = pmn(P2, Q1);  C[4] = pmx(P2, Q1);
    C[5] = pmn(P3, Q2);  C[6] = pmx(P3, Q2);
    C[7] = pmn(P4, qo1); C[8] = pmx(P4, qo1);
    C[9] = ro1;
}

// Middle six (ranks 7..12, sorted) of merge(S10,T10): pruned Batcher merge.
__device__ __forceinline__ void mid6p(const u32 (&S)[10], const u32 (&T)[10], u32 (&V)[6]) {
    u32 e1 = pmx(S[0], T[0]);
    u32 o0 = pmn(S[8], T[8]);
    u32 R1 = pmn(e1, o0), R2 = pmx(e1, o0);
    u32 s0 = pmn(S[4], T[4]), s1 = pmx(S[4], T[4]);
    u32 qe1 = pmx(S[2], T[2]), qo0 = pmn(S[6], T[6]);
    u32 Q1 = pmn(qe1, qo0), Q2 = pmx(qe1, qo0);
    u32 E4 = pmx(pmx(R1, s0), Q1);
    u32 P3 = pmn(R2, s1);
    u32 E5 = pmn(P3, Q2), E6 = pmx(P3, Q2);
    u32 f1 = pmx(S[1], T[1]);
    u32 g0 = pmn(S[9], T[9]);
    u32 R1o = pmn(f1, g0), R2o = pmx(f1, g0);
    u32 t0 = pmn(S[5], T[5]), t1 = pmx(S[5], T[5]);
    u32 qf1 = pmx(S[3], T[3]), qg0 = pmn(S[7], T[7]);
    u32 Q1o = pmn(qf1, qg0), Q2o = pmx(qf1, qg0);
    u32 P2o = pmx(R1o, t0);
    u32 O3 = pmn(P2o, Q1o), O4 = pmx(P2o, Q1o);
    u32 O5 = pmn(pmn(R2o, t1), Q2o);
    V[0] = pmn(E4, O3); V[1] = pmx(E4, O3);
    V[2] = pmn(E5, O4); V[3] = pmx(E5, O4);
    V[4] = pmn(E6, O5); V[5] = pmx(E6, O5);
}

// rank-5 of V(6 sorted) u G(5 sorted): max over splits of min(V[i],G[j]).
__device__ __forceinline__ u32 rank5p(const u32 (&V)[6], const u32 (&G)[5]) {
    u32 m1 = pmn(V[1], G[4]);
    u32 m2 = pmn(V[2], G[3]);
    u32 m3 = pmn(V[3], G[2]);
    u32 m4 = pmn(V[4], G[1]);
    u32 m5 = pmn(V[5], G[0]);
    return pmx(pmx(pmx(V[0], m1), m2), pmx(pmx(m3, m4), m5));
}

// Copy-sort4: T = sorted(v[0..3]), v untouched. Optimal 5-CE network.
__device__ __forceinline__ void sort4p_copy(const u32* v, u32 (&T)[4]) {
    u32 t0 = v[0], t1 = v[1], t2 = v[2], t3 = v[3], u;
    u = pmn(t0, t1); t1 = pmx(t0, t1); t0 = u;
    u = pmn(t2, t3); t3 = pmx(t2, t3); t2 = u;
    u = pmn(t0, t2); t2 = pmx(t0, t2); t0 = u;
    u = pmn(t1, t3); t3 = pmx(t1, t3); t1 = u;
    u = pmn(t1, t2); t2 = pmx(t1, t2); t1 = u;
    T[0] = t0; T[1] = t1; T[2] = t2; T[3] = t3;
}

// Insert e into sorted T[0..3] -> sorted d[0..4]. 4 CEs.
__device__ __forceinline__ void ins5p(u32 e, const u32 (&T)[4], u32 (&d)[5]) {
    u32 u;
    d[0] = pmn(e, T[0]); u = pmx(e, T[0]);
    d[1] = pmn(u, T[1]); u = pmx(u, T[1]);
    d[2] = pmn(u, T[2]); u = pmx(u, T[2]);
    d[3] = pmn(u, T[3]); d[4] = pmx(u, T[3]);
}

__global__ __launch_bounds__(256, 2) void median5x5_all(const u32* __restrict__ in,
                                                        u32* __restrict__ out) {
    const int W = 2048, H = 2048;

    // Bijective XCD swizzle: 1536 blocks, 8 XCDs, 192/XCD, x-fastest then y, z.
    const int id = blockIdx.x;
    const int w = (id & 7) * 192 + (id >> 3);
    const int bx = w & 3;
    const int yb = (w >> 2) & 127;
    const int z = w >> 9;

    const int g = bx * 64 + threadIdx.x;       // 0..255; pixels 8g..8g+7
    const int y = 16 * yb + 4 * threadIdx.y;   // outputs rows y..y+3
    const size_t plane = (size_t)z * (size_t)(H * W);
    const u32* __restrict__ src = in + plane;

    const int base = 8 * g;
    const int colA = (base - 2) < 0 ? 0 : (base - 2);        // raw[0,1]
    const int colD = (base + 8) > 2046 ? 2046 : (base + 8);  // raw[10,11]
    const bool gl = (g == 0);
    const bool gr = (g == 255);

    // Stage 8 rows (y-2 .. y+5, y-clamped) as packed bf16 columns:
    // P[j][r] = pack(bf16(col base-2+j) lo, bf16(col base+2+j) hi).
    // Branch-free x fixups: raw[1] = gl ? A.x : A.y ; raw[10] = gr ? D.y : D.x.
    u32 P[8][8];
#pragma unroll
    for (int r = 0; r < 8; ++r) {
        int yy = y - 2 + r;
        yy = yy < 0 ? 0 : (yy > H - 1 ? H - 1 : yy);
        const u32* rowp = src + (size_t)yy * W;
        uint2 a = *(const uint2*)(rowp + colA);
        uint4 b = *(const uint4*)(rowp + base);
        uint4 c = *(const uint4*)(rowp + base + 4);
        uint2 d = *(const uint2*)(rowp + colD);
        u32 raw[12];
        raw[0] = a.x;
        raw[1] = gl ? a.x : a.y;
        raw[2] = b.x;  raw[3] = b.y;  raw[4] = b.z;  raw[5] = b.w;
        raw[6] = c.x;  raw[7] = c.y;  raw[8] = c.z;  raw[9] = c.w;
        raw[10] = gr ? d.y : d.x;
        raw[11] = d.y;
#pragma unroll
        for (int j = 0; j < 8; ++j)
            P[j][r] = __builtin_amdgcn_perm(raw[j + 4], raw[j], 0x07060302u);
    }

    // DO_ROW: one output row at y+H; S[j] = insert P[j][EIDX] into sorted T[j].
    // Output stores are NON-TEMPORAL (write-once stream; keep L2 for input).
#define DO_ROW(T, EIDX, H)                                                    \
    {                                                                         \
        u32 S[8][5];                                                          \
        _Pragma("unroll") for (int j = 0; j < 8; ++j)                         \
            ins5p(P[j][EIDX], T[j], S[j]);                                    \
        u32 M12[10], M34[10], M56[10];                                        \
        merge55p(S[1], S[2], M12);                                            \
        merge55p(S[3], S[4], M34);                                            \
        merge55p(S[5], S[6], M56);                                            \
        u32 VA[6], VB[6];                                                     \
        mid6p(M12, M34, VA);                                                  \
        mid6p(M34, M56, VB);                                                  \
        u32 o0 = rank5p(VA, S[0]);                                            \
        u32 o1 = rank5p(VA, S[5]);                                            \
        u32 o2 = rank5p(VB, S[2]);                                            \
        u32 o3 = rank5p(VB, S[7]);                                            \
        u32* op = out + plane + (size_t)(y + (H)) * W + base;                 \
        u32x4 e_, o_;                                                         \
        e_.x = o0 << 16; e_.y = o1 << 16; e_.z = o2 << 16; e_.w = o3 << 16;   \
        o_.x = o0 & 0xffff0000u; o_.y = o1 & 0xffff0000u;                     \
        o_.z = o2 & 0xffff0000u; o_.w = o3 & 0xffff0000u;                     \
        __builtin_nontemporal_store(e_, (u32x4*)(op));                        \
        __builtin_nontemporal_store(o_, (u32x4*)(op + 4));                    \
    }

    // Group A: outputs y, y+1 share sorted staged rows 1..4.
    {
        u32 T[8][4];
#pragma unroll
        for (int j = 0; j < 8; ++j) sort4p_copy(&P[j][1], T[j]);
        DO_ROW(T, 0, 0)   // window staged rows 0..4
        DO_ROW(T, 5, 1)   // window staged rows 1..5
    }
    // Group B: outputs y+2, y+3 share sorted staged rows 3..6.
    {
        u32 T[8][4];
#pragma unroll
        for (int j = 0; j < 8; ++j) sort4p_copy(&P[j][3], T[j]);
        DO_ROW(T, 2, 2)   // window staged rows 2..6
        DO_ROW(T, 7, 3)   // window staged rows 3..7
    }
#undef DO_ROW
}

extern "C" void kernel_launch(void* const* d_in, const int* in_sizes, int n_in,
                              void* d_out, int out_size, void* d_ws, size_t ws_size,
                              hipStream_t stream) {
    const u32* in = (const u32*)d_in[0];
    u32* out = (u32*)d_out;
    dim3 block(64, 4, 1);
    dim3 grid(1536, 1, 1);
    hipLaunchKernelGGL(median5x5_all, grid, block, 0, stream, in, out);
}

// Round 18
// 26.172 us; speedup vs baseline: 1.0402x; 1.0402x over previous
//
#include <hip/hip_runtime.h>

// 5x5 median, replicate borders, C=3, H=W=2048, fp32.
// R18 = R15 (4-row vertical sharing, packed-bf16 network, XCD swizzle)
//     + occupancy push: __launch_bounds__(256,3) (VGPR cap ~168 -> 3 waves/SIMD)
//     + per-row load->pack (1 row of raw staging live at a time, not 8)
//     + regular stores (NT was neutral/worse, reverted).

typedef unsigned int u32;

__device__ __forceinline__ u32 pmn(u32 a, u32 b) {
    u32 r;
    asm("v_pk_min_u16 %0, %1, %2" : "=v"(r) : "v"(a), "v"(b));
    return r;
}
__device__ __forceinline__ u32 pmx(u32 a, u32 b) {
    u32 r;
    asm("v_pk_max_u16 %0, %1, %2" : "=v"(r) : "v"(a), "v"(b));
    return r;
}

// Batcher odd-even merge of two sorted 5-arrays -> sorted 10 (packed). 13 CEs.
__device__ __forceinline__ void merge55p(const u32 (&A)[5], const u32 (&B)[5], u32 (&C)[10]) {
    u32 re0 = pmn(A[0], B[0]), re1 = pmx(A[0], B[0]);
    u32 ro0 = pmn(A[4], B[4]), ro1 = pmx(A[4], B[4]);
    u32 R1 = pmn(re1, ro0), R2 = pmx(re1, ro0);
    u32 s0 = pmn(A[2], B[2]), s1 = pmx(A[2], B[2]);
    u32 P1 = pmn(R1, s0), P2 = pmx(R1, s0);
    u32 P3 = pmn(R2, s1), P4 = pmx(R2, s1);
    u32 qe0 = pmn(A[1], B[1]), qe1 = pmx(A[1], B[1]);
    u32 qo0 = pmn(A[3], B[3]), qo1 = pmx(A[3], B[3]);
    u32 Q1 = pmn(qe1, qo0), Q2 = pmx(qe1, qo0);
    C[0] = re0;
    C[1] = pmn(P1, qe0); C[2] = pmx(P1, qe0);
    C[3] = pmn(P2, Q1);  C[4] = pmx(P2, Q1);
    C[5] = pmn(P3, Q2);  C[6] = pmx(P3, Q2);
    C[7] = pmn(P4, qo1); C[8] = pmx(P4, qo1);
    C[9] = ro1;
}

// Middle six (ranks 7..12, sorted) of merge(S10,T10): pruned Batcher merge.
__device__ __forceinline__ void mid6p(const u32 (&S)[10], const u32 (&T)[10], u32 (&V)[6]) {
    u32 e1 = pmx(S[0], T[0]);
    u32 o0 = pmn(S[8], T[8]);
    u32 R1 = pmn(e1, o0), R2 = pmx(e1, o0);
    u32 s0 = pmn(S[4], T[4]), s1 = pmx(S[4], T[4]);
    u32 qe1 = pmx(S[2], T[2]), qo0 = pmn(S[6], T[6]);
    u32 Q1 = pmn(qe1, qo0), Q2 = pmx(qe1, qo0);
    u32 E4 = pmx(pmx(R1, s0), Q1);
    u32 P3 = pmn(R2, s1);
    u32 E5 = pmn(P3, Q2), E6 = pmx(P3, Q2);
    u32 f1 = pmx(S[1], T[1]);
    u32 g0 = pmn(S[9], T[9]);
    u32 R1o = pmn(f1, g0), R2o = pmx(f1, g0);
    u32 t0 = pmn(S[5], T[5]), t1 = pmx(S[5], T[5]);
    u32 qf1 = pmx(S[3], T[3]), qg0 = pmn(S[7], T[7]);
    u32 Q1o = pmn(qf1, qg0), Q2o = pmx(qf1, qg0);
    u32 P2o = pmx(R1o, t0);
    u32 O3 = pmn(P2o, Q1o), O4 = pmx(P2o, Q1o);
    u32 O5 = pmn(pmn(R2o, t1), Q2o);
    V[0] = pmn(E4, O3); V[1] = pmx(E4, O3);
    V[2] = pmn(E5, O4); V[3] = pmx(E5, O4);
    V[4] = pmn(E6, O5); V[5] = pmx(E6, O5);
}

// rank-5 of V(6 sorted) u G(5 sorted): max over splits of min(V[i],G[j]).
__device__ __forceinline__ u32 rank5p(const u32 (&V)[6], const u32 (&G)[5]) {
    u32 m1 = pmn(V[1], G[4]);
    u32 m2 = pmn(V[2], G[3]);
    u32 m3 = pmn(V[3], G[2]);
    u32 m4 = pmn(V[4], G[1]);
    u32 m5 = pmn(V[5], G[0]);
    return pmx(pmx(pmx(V[0], m1), m2), pmx(pmx(m3, m4), m5));
}

// Copy-sort4: T = sorted(v[0..3]), v untouched. Optimal 5-CE network.
__device__ __forceinline__ void sort4p_copy(const u32* v, u32 (&T)[4]) {
    u32 t0 = v[0], t1 = v[1], t2 = v[2], t3 = v[3], u;
    u = pmn(t0, t1); t1 = pmx(t0, t1); t0 = u;
    u = pmn(t2, t3); t3 = pmx(t2, t3); t2 = u;
    u = pmn(t0, t2); t2 = pmx(t0, t2); t0 = u;
    u = pmn(t1, t3); t3 = pmx(t1, t3); t1 = u;
    u = pmn(t1, t2); t2 = pmx(t1, t2); t1 = u;
    T[0] = t0; T[1] = t1; T[2] = t2; T[3] = t3;
}

// Insert e into sorted T[0..3] -> sorted d[0..4]. 4 CEs.
__device__ __forceinline__ void ins5p(u32 e, const u32 (&T)[4], u32 (&d)[5]) {
    u32 u;
    d[0] = pmn(e, T[0]); u = pmx(e, T[0]);
    d[1] = pmn(u, T[1]); u = pmx(u, T[1]);
    d[2] = pmn(u, T[2]); u = pmx(u, T[2]);
    d[3] = pmn(u, T[3]); d[4] = pmx(u, T[3]);
}

__global__ __launch_bounds__(256, 3) void median5x5_all(const u32* __restrict__ in,
                                                        u32* __restrict__ out) {
    const int W = 2048, H = 2048;

    // Bijective XCD swizzle: 1536 blocks, 8 XCDs, 192/XCD, x-fastest then y, z.
    const int id = blockIdx.x;
    const int w = (id & 7) * 192 + (id >> 3);
    const int bx = w & 3;
    const int yb = (w >> 2) & 127;
    const int z = w >> 9;

    const int g = bx * 64 + threadIdx.x;       // 0..255; pixels 8g..8g+7
    const int y = 16 * yb + 4 * threadIdx.y;   // outputs rows y..y+3
    const size_t plane = (size_t)z * (size_t)(H * W);
    const u32* __restrict__ src = in + plane;

    const int base = 8 * g;
    const int colA = (base - 2) < 0 ? 0 : (base - 2);        // raw[0,1]
    const int colD = (base + 8) > 2046 ? 2046 : (base + 8);  // raw[10,11]
    const bool gl = (g == 0);
    const bool gr = (g == 255);

    // Stage 8 rows (y-2 .. y+5, y-clamped) as packed bf16 columns, packing
    // each row right after its loads (keeps <=1 row of raw staging live ->
    // fits the 168-VGPR cap without spills).
    // P[j][r] = pack(bf16(col base-2+j) lo, bf16(col base+2+j) hi).
    // Branch-free x fixups: raw[1] = gl ? A.x : A.y ; raw[10] = gr ? D.y : D.x.
    u32 P[8][8];
#pragma unroll
    for (int r = 0; r < 8; ++r) {
        int yy = y - 2 + r;
        yy = yy < 0 ? 0 : (yy > H - 1 ? H - 1 : yy);
        const u32* rowp = src + (size_t)yy * W;
        uint2 a = *(const uint2*)(rowp + colA);
        uint4 b = *(const uint4*)(rowp + base);
        uint4 c = *(const uint4*)(rowp + base + 4);
        uint2 d = *(const uint2*)(rowp + colD);
        u32 raw[12];
        raw[0] = a.x;
        raw[1] = gl ? a.x : a.y;
        raw[2] = b.x;  raw[3] = b.y;  raw[4] = b.z;  raw[5] = b.w;
        raw[6] = c.x;  raw[7] = c.y;  raw[8] = c.z;  raw[9] = c.w;
        raw[10] = gr ? d.y : d.x;
        raw[11] = d.y;
#pragma unroll
        for (int j = 0; j < 8; ++j)
            P[j][r] = __builtin_amdgcn_perm(raw[j + 4], raw[j], 0x07060302u);
    }

    // DO_ROW: one output row at y+H; S[j] = insert P[j][EIDX] into sorted T[j].
#define DO_ROW(T, EIDX, H)                                                    \
    {                                                                         \
        u32 S[8][5];                                                          \
        _Pragma("unroll") for (int j = 0; j < 8; ++j)                         \
            ins5p(P[j][EIDX], T[j], S[j]);                                    \
        u32 M12[10], M34[10], M56[10];                                        \
        merge55p(S[1], S[2], M12);                                            \
        merge55p(S[3], S[4], M34);                                            \
        merge55p(S[5], S[6], M56);                                            \
        u32 VA[6], VB[6];                                                     \
        mid6p(M12, M34, VA);                                                  \
        mid6p(M34, M56, VB);                                                  \
        u32 o0 = rank5p(VA, S[0]);                                            \
        u32 o1 = rank5p(VA, S[5]);                                            \
        u32 o2 = rank5p(VB, S[2]);                                            \
        u32 o3 = rank5p(VB, S[7]);                                            \
        u32* op = out + plane + (size_t)(y + (H)) * W + base;                 \
        uint4 e_, o_;                                                         \
        e_.x = o0 << 16; e_.y = o1 << 16; e_.z = o2 << 16; e_.w = o3 << 16;   \
        o_.x = o0 & 0xffff0000u; o_.y = o1 & 0xffff0000u;                     \
        o_.z = o2 & 0xffff0000u; o_.w = o3 & 0xffff0000u;                     \
        *(uint4*)(op) = e_;                                                   \
        *(uint4*)(op + 4) = o_;                                               \
    }

    // Group A: outputs y, y+1 share sorted staged rows 1..4.
    {
        u32 T[8][4];
#pragma unroll
        for (int j = 0; j < 8; ++j) sort4p_copy(&P[j][1], T[j]);
        DO_ROW(T, 0, 0)   // window staged rows 0..4
        DO_ROW(T, 5, 1)   // window staged rows 1..5
    }
    // Group B: outputs y+2, y+3 share sorted staged rows 3..6.
    {
        u32 T[8][4];
#pragma unroll
        for (int j = 0; j < 8; ++j) sort4p_copy(&P[j][3], T[j]);
        DO_ROW(T, 2, 2)   // window staged rows 2..6
        DO_ROW(T, 7, 3)   // window staged rows 3..7
    }
#undef DO_ROW
}

extern "C" void kernel_launch(void* const* d_in, const int* in_sizes, int n_in,
                              void* d_out, int out_size, void* d_ws, size_t ws_size,
                              hipStream_t stream) {
    const u32* in = (const u32*)d_in[0];
    u32* out = (u32*)d_out;
    dim3 block(64, 4, 1);
    dim3 grid(1536, 1, 1);
    hipLaunchKernelGGL(median5x5_all, grid, block, 0, stream, in, out);
}